// Round 2
// baseline (198.761 us; speedup 1.0000x reference)
//
#include <hip/hip_runtime.h>

#define NNODES 50000
#define FEAT 256
#define NH 8
#define DHEAD 32
#define DEG 16
#define CDIM 256  // NH*DHEAD

typedef __attribute__((ext_vector_type(4))) float floatx4;
typedef __attribute__((ext_vector_type(8))) short shortx8;
typedef __attribute__((ext_vector_type(8))) unsigned short ushortx8;

__device__ __forceinline__ unsigned short f2bf(float f) {
  union { float f; unsigned u; } v; v.f = f;
  unsigned r = v.u + 0x7fffu + ((v.u >> 16) & 1u);  // RN-even
  return (unsigned short)(r >> 16);
}
__device__ __forceinline__ float bf2f(unsigned short b) {
  union { unsigned u; float f; } v; v.u = ((unsigned)b) << 16;
  return v.f;
}

// Kernel 0: W [H][F][DH] fp32 -> Wt2 bf16 in MFMA-fragment-major order:
// Wt2[((cgrp*8 + kt)*64 + lane)*8 + jj] = element (c = cgrp*16 + (lane&15),
// k = kt*32 + (lane>>4)*8 + jj). Wave B-frag load = one coalesced 1KB load.
__global__ __launch_bounds__(256) void convert_wt(
    const float* __restrict__ W, unsigned short* __restrict__ Wt2) {
  int t = blockIdx.x * 256 + threadIdx.x;
#pragma unroll
  for (int p = 0; p < 4; ++p) {
    int idx = t * 4 + p;  // [0, 65536)
    int jj = idx & 7;
    int l = (idx >> 3) & 63;
    int kt = (idx >> 9) & 7;
    int cgrp = idx >> 12;
    int c = cgrp * 16 + (l & 15);
    int f = kt * 32 + ((l >> 4) << 3) + jj;
    Wt2[idx] = f2bf(W[(size_t)(c >> 5) * (FEAT * DHEAD) + (size_t)f * DHEAD + (c & 31)]);
  }
}

// Kernel 1 (fused): Whb[n][c] = bf16(sum_k h[n][k]*W[c][k] + bW[c]), plus
// s1g[n][h] / s2g[n][h] (s2 includes a_bias) in the epilogue.
// 64x256 tile; A staged to LDS once (fp32->bf16 in regs); barrier-free
// K-loop: A frags via ds_read_b128, B frags direct global->VGPR from
// L2-resident fragment-major Wt2.
__global__ __launch_bounds__(256) void gemm_fused(
    const float* __restrict__ h, const unsigned short* __restrict__ Wt2,
    const float* __restrict__ bW, const float* __restrict__ a_src,
    const float* __restrict__ a_dst, const float* __restrict__ a_bias,
    unsigned short* __restrict__ Whb, float* __restrict__ s1g,
    float* __restrict__ s2g) {
  __shared__ unsigned short As2[8 * 4 * 64 * 8];  // 32 KB, fragment-major
  const int tid = threadIdx.x;
  const int w = tid >> 6, lane = tid & 63;
  const int mrow = lane & 15, quad = lane >> 4;
  const int row0 = blockIdx.x * 64;

  {  // Stage A once: thread covers (row = w*16 + mrow, cols quad*8..+8) x 8 kt
    int grow = row0 + w * 16 + mrow;
    if (grow > NNODES - 1) grow = NNODES - 1;
    const float* hp = h + (size_t)grow * FEAT + quad * 8;
#pragma unroll
    for (int kt = 0; kt < 8; ++kt) {
      float4 v0 = *(const float4*)(hp + kt * 32);
      float4 v1 = *(const float4*)(hp + kt * 32 + 4);
      shortx8 a8;
      a8[0] = (short)f2bf(v0.x); a8[1] = (short)f2bf(v0.y);
      a8[2] = (short)f2bf(v0.z); a8[3] = (short)f2bf(v0.w);
      a8[4] = (short)f2bf(v1.x); a8[5] = (short)f2bf(v1.y);
      a8[6] = (short)f2bf(v1.z); a8[7] = (short)f2bf(v1.w);
      *(shortx8*)&As2[((kt * 4 + w) * 64 + lane) * 8] = a8;
    }
  }
  __syncthreads();

  floatx4 acc[4][4] = {};
#pragma unroll
  for (int kt = 0; kt < 8; ++kt) {
    shortx8 af[4], bfr[4];
#pragma unroll
    for (int ni = 0; ni < 4; ++ni) {
      int cgrp = w * 4 + ni;
      bfr[ni] = *(const shortx8*)&Wt2[((size_t)(cgrp * 8 + kt) * 64 + lane) * 8];
    }
#pragma unroll
    for (int mi = 0; mi < 4; ++mi)
      af[mi] = *(const shortx8*)&As2[((kt * 4 + mi) * 64 + lane) * 8];
#pragma unroll
    for (int mi = 0; mi < 4; ++mi)
#pragma unroll
      for (int ni = 0; ni < 4; ++ni)
        acc[mi][ni] = __builtin_amdgcn_mfma_f32_16x16x32_bf16(
            af[mi], bfr[ni], acc[mi][ni], 0, 0, 0);
  }

  // Epilogue: bias + bf16 store + fused s1/s2 per-head dots.
  // Wave w cols: col = w*64 + ni*16 + mrow; heads h0 = 2w (ni 0,1), h1 = 2w+1.
  float aw_s[4], aw_d[4], bias[4];
#pragma unroll
  for (int ni = 0; ni < 4; ++ni) {
    int col = w * 64 + ni * 16 + mrow;
    aw_s[ni] = a_src[col];
    aw_d[ni] = a_dst[col];
    bias[ni] = bW[col];
  }
  float ab0 = a_bias[w * 2], ab1 = a_bias[w * 2 + 1];
#pragma unroll
  for (int mi = 0; mi < 4; ++mi) {
#pragma unroll
    for (int ni = 0; ni < 4; ++ni) {
      int col = w * 64 + ni * 16 + mrow;
#pragma unroll
      for (int r = 0; r < 4; ++r) {
        int row = row0 + mi * 16 + quad * 4 + r;
        float val = acc[mi][ni][r] + bias[ni];
        acc[mi][ni][r] = val;  // keep fp32 for s1/s2
        if (row < NNODES) Whb[(size_t)row * CDIM + col] = f2bf(val);
      }
    }
#pragma unroll
    for (int r = 0; r < 4; ++r) {
      float s1h0 = acc[mi][0][r] * aw_s[0] + acc[mi][1][r] * aw_s[1];
      float s1h1 = acc[mi][2][r] * aw_s[2] + acc[mi][3][r] * aw_s[3];
      float s2h0 = acc[mi][0][r] * aw_d[0] + acc[mi][1][r] * aw_d[1];
      float s2h1 = acc[mi][2][r] * aw_d[2] + acc[mi][3][r] * aw_d[3];
#pragma unroll
      for (int off = 1; off < 16; off <<= 1) {
        s1h0 += __shfl_xor(s1h0, off, 64);
        s1h1 += __shfl_xor(s1h1, off, 64);
        s2h0 += __shfl_xor(s2h0, off, 64);
        s2h1 += __shfl_xor(s2h1, off, 64);
      }
      if (mrow == 0) {
        int row = row0 + mi * 16 + quad * 4 + r;
        if (row < NNODES) {
          float2 s1v; s1v.x = s1h0; s1v.y = s1h1;
          float2 s2v; s2v.x = s2h0 + ab0; s2v.y = s2h1 + ab1;
          *(float2*)&s1g[(size_t)row * NH + w * 2] = s1v;
          *(float2*)&s2g[(size_t)row * NH + w * 2] = s2v;
        }
      }
    }
  }
}

// Kernel 2: one node per wave, fully wave-local (no LDS, no __syncthreads).
// Half-wave per gathered row (16B/lane): lanes<32 accumulate even edges,
// lanes>=32 odd edges. Softmax is wave-parallel: lane owns scores
// (e=lane>>3, h=lane&7) and (e+8, h); head-group reduce via shfl_xor 8/16/32.
// Score loads are issued BEFORE the 8 row gathers so the compiler's counted
// vmcnt retires them without draining the row loads.
__global__ __launch_bounds__(256) void aggregate(
    const unsigned short* __restrict__ Whb, const float* __restrict__ s1g,
    const float* __restrict__ s2g, const int* __restrict__ src,
    float* __restrict__ out) {
  const int lane = threadIdx.x & 63;
  const int n = blockIdx.x * 4 + (threadIdx.x >> 6);
  const int half = lane >> 5;   // 0: even edges, 1: odd edges
  const int l32 = lane & 31;    // column group: cols l32*8 .. +8
  const int hsc = lane & 7;     // head this lane scores
  const int hacc = l32 >> 2;    // head this lane accumulates (cols/32)

  // src row: 16 ints, one 4B load per lane (replicated x4, L1-broadcast)
  int s0 = src[(size_t)n * DEG + (lane & 15)];
  float s2v = s2g[(size_t)n * NH + hsc];  // a_bias already folded in

  // ---- score-operand gathers (issued first) ----
  int se0 = __shfl(s0, lane >> 3);        // src of edge  e  = lane>>3
  int se1 = __shfl(s0, (lane >> 3) + 8);  // src of edge e+8
  float s1a = s1g[(size_t)se0 * NH + hsc];
  float s1b = s1g[(size_t)se1 * NH + hsc];

  // ---- row gathers: 8 x 16B per lane, half-wave covers one 512B row ----
  int rsrc[8];
#pragma unroll
  for (int t = 0; t < 8; ++t) rsrc[t] = __shfl(s0, 2 * t + half);
  ushortx8 vrow[8];
#pragma unroll
  for (int t = 0; t < 8; ++t)
    vrow[t] = *(const ushortx8*)&Whb[(size_t)rsrc[t] * CDIM + l32 * 8];

  // ---- wave-parallel softmax over the 16 edges of head hsc ----
  float sc0 = s1a + s2v; sc0 = sc0 > 0.f ? sc0 : 0.2f * sc0;  // leaky relu
  float sc1 = s1b + s2v; sc1 = sc1 > 0.f ? sc1 : 0.2f * sc1;
  float m = fmaxf(sc0, sc1);
  m = fmaxf(m, __shfl_xor(m, 8));
  m = fmaxf(m, __shfl_xor(m, 16));
  m = fmaxf(m, __shfl_xor(m, 32));
  float ex0 = __expf(sc0 - m), ex1 = __expf(sc1 - m);
  float sum = ex0 + ex1;
  sum += __shfl_xor(sum, 8);
  sum += __shfl_xor(sum, 16);
  sum += __shfl_xor(sum, 32);
  float inv = 1.f / sum;
  float w0 = ex0 * inv;  // attn weight of (edge lane>>3,     head lane&7)
  float w1 = ex1 * inv;  // attn weight of (edge (lane>>3)+8, head lane&7)

  // ---- pull the 8 weights this lane needs: (e = 2t+half, h = hacc) ----
  float wgt[8];
#pragma unroll
  for (int t = 0; t < 4; ++t) {
    int sl = ((2 * t + half) << 3) | hacc;  // producer lane of (e&7, hacc)
    wgt[t] = __shfl(w0, sl);                // e = 2t+half      (< 8)
    wgt[t + 4] = __shfl(w1, sl);            // e = 2t+half + 8
  }

  // ---- weighted accumulate over this half's 8 edges ----
  float acc[8] = {0.f, 0.f, 0.f, 0.f, 0.f, 0.f, 0.f, 0.f};
#pragma unroll
  for (int t = 0; t < 8; ++t) {
    ushortx8 v = vrow[t];
    float w = wgt[t];
#pragma unroll
    for (int j = 0; j < 8; ++j) acc[j] += w * bf2f(v[j]);
  }

  // ---- combine even/odd halves; each lane stores 16B (static indices) ----
#pragma unroll
  for (int j = 0; j < 8; ++j) acc[j] += __shfl_xor(acc[j], 32);
  floatx4 o;
  o.x = half ? acc[4] : acc[0];
  o.y = half ? acc[5] : acc[1];
  o.z = half ? acc[6] : acc[2];
  o.w = half ? acc[7] : acc[3];
  __builtin_nontemporal_store(
      o, (floatx4*)&out[(size_t)n * CDIM + l32 * 8 + half * 4]);
}

extern "C" void kernel_launch(void* const* d_in, const int* in_sizes, int n_in,
                              void* d_out, int out_size, void* d_ws, size_t ws_size,
                              hipStream_t stream) {
  const float* h = (const float*)d_in[0];
  const float* W = (const float*)d_in[1];
  const float* bW = (const float*)d_in[2];
  const float* a_src = (const float*)d_in[3];
  const float* a_dst = (const float*)d_in[4];
  const float* a_bias = (const float*)d_in[5];
  const int* src = (const int*)d_in[6];
  // d_in[7] (dst) unused: dst = repeat(arange(N), DEG) structurally.
  float* out = (float*)d_out;

  unsigned short* Whb = (unsigned short*)d_ws;          // [N][256] bf16, 25.6 MB
  unsigned short* Wt2 = Whb + (size_t)NNODES * CDIM;    // [256][256] bf16, 131 KB
  float* s1g = (float*)(Wt2 + CDIM * FEAT);             // [N][8] fp32, 1.6 MB
  float* s2g = s1g + (size_t)NNODES * NH;               // [N][8] fp32, 1.6 MB

  convert_wt<<<64, 256, 0, stream>>>(W, Wt2);
  gemm_fused<<<(NNODES + 63) / 64, 256, 0, stream>>>(h, Wt2, bW, a_src, a_dst,
                                                     a_bias, Whb, s1g, s2g);
  aggregate<<<NNODES / 4, 256, 0, stream>>>(Whb, s1g, s2g, src, out);
}